// Round 4
// baseline (246409.448 us; speedup 1.0000x reference)
//
#include <hip/hip_runtime.h>
#include <cstdint>
#include <cstddef>

// PlainRNN fused: h_{t+1} = tanh(h_t @ W_eff + b_eff), traj[t] = h_t @ W_h2o + b_h2o
// W_eff = W_h2h + W_h2o @ W_i2h  (recurrence composition removes x from the loop)
//
// Persistent kernel: 16 groups (16 batch rows each) x 16 blocks (72 of 1152 cols each).
// Groups formed DYNAMICALLY per-XCD (HW_REG_XCC_ID + per-XCD slot counter): all 16
// members share one XCD L2. ALL inter-block communication meets at that L2:
//   h data:  plain stores (write-through to L2)  ->  sc0 loads (L1-bypass, L2-hit)
//   barrier: WORKGROUP-scope atomic RMW (no sc bits => executes in local L2)
//            ->  sc0 poll loads (read the same L2)
// NO agent-scope fences (no buffer_wbl2/inv), NO MALL round-trips in the loop.
// R4 fixes vs R3: arrival atomic was agent-scope (executes at MALL) while poll read
// local L2 => frozen counter => per-step spin timeout => harness timeout. Arrival is
// now workgroup-scope (local L2). Spin bound 4096 (fail visibly, never hang). Slot
// overflow exits cleanly instead of OOB-writing out.

#define BATCH  256
#define INPUT  128
#define HIDDEN 1024
#define OUTPUT 128
#define TSTEPS 512
#define NCAT   1152
#define NTILE  72
#define GROUPS 16
#define MEMB   16

// workspace layout (bytes)
#define WS_WFRAG 0u
#define WS_BEFF  2621440u
#define WS_HBUF  2629632u
#define WS_BAR   3678208u
// bar[] u32: [0..511] arrival counters (group g at g*32, one 128B line each)
//            [512..767] per-XCD slot counters (xcc at 512 + xcc*32)
#define BAR_U32S 768

typedef _Float16 f16;
typedef _Float16 v8h __attribute__((ext_vector_type(8)));
typedef float    v4f __attribute__((ext_vector_type(4)));

__device__ __forceinline__ float fast_tanh(float x){
  float e = __expf(2.0f * x);
  return (e - 1.0f) / (e + 1.0f);
}

// ---- bias composition
__global__ void k_bias(const float* __restrict__ bi2h, const float* __restrict__ bh2h,
                       const float* __restrict__ bh2o, const float* __restrict__ Wi2h,
                       float* __restrict__ beff){
  int n = blockIdx.x*256 + threadIdx.x;
  if (n >= 1168) return;
  float v = 0.f;
  if (n < HIDDEN){
    v = bi2h[n] + bh2h[n];
    for (int j=0;j<INPUT;j++) v += bh2o[j]*Wi2h[j*HIDDEN + n];
  } else if (n < NCAT){
    v = bh2o[n - HIDDEN];
  }
  beff[n] = v;
}

// ---- h_1 = tanh(x0 @ W_i2h + b_i2h + b_h2h)
__global__ void k_h1(const float* __restrict__ x0, const float* __restrict__ Wi2h,
                     const float* __restrict__ bi2h, const float* __restrict__ bh2h,
                     f16* __restrict__ hbuf){
  int idx = blockIdx.x*256 + threadIdx.x;
  int m = idx >> 10, n = idx & 1023;
  float acc = bi2h[n] + bh2h[n];
  const float* xr = x0 + m*INPUT;
  for (int j=0;j<INPUT;j++) acc += xr[j]*Wi2h[j*HIDDEN + n];
  hbuf[idx] = (f16)fast_tanh(acc);
}

// ---- traj[0] = x_0
__global__ void k_copy0(const float* __restrict__ x0, float* __restrict__ out){
  int i = blockIdx.x*256 + threadIdx.x;
  out[i] = x0[i];
}

// ---- W fragment packing: [mem 16][wave 4][kk 8][c 5][lane 64][8 halves]
__global__ void k_wfrag(const float* __restrict__ Wh2h, const float* __restrict__ Wh2o,
                        const float* __restrict__ Wi2h, f16* __restrict__ Wfrag){
  int gid = blockIdx.x*256 + threadIdx.x;
  int lane = gid & 63;
  int fi = gid >> 6;
  int c = fi % 5, kk = (fi/5) & 7, wv = (fi/40) & 3, mem = fi/160;
  int k0 = wv*256 + kk*32 + (lane>>4)*8;
  int n  = mem*NTILE + c*16 + (lane & 15);
  f16 vals[8];
  if (n >= NCAT){
    #pragma unroll
    for (int j=0;j<8;j++) vals[j] = (f16)0.f;
  } else if (n >= HIDDEN){
    #pragma unroll
    for (int j=0;j<8;j++) vals[j] = (f16)Wh2o[(k0+j)*OUTPUT + (n-HIDDEN)];
  } else {
    float acc[8];
    #pragma unroll
    for (int j=0;j<8;j++) acc[j] = Wh2h[(k0+j)*HIDDEN + n];
    for (int q=0;q<INPUT;q++){
      float wi = Wi2h[q*HIDDEN + n];
      #pragma unroll
      for (int j=0;j<8;j++) acc[j] += Wh2o[(k0+j)*OUTPUT + q]*wi;
    }
    #pragma unroll
    for (int j=0;j<8;j++) vals[j] = (f16)acc[j];
  }
  v8h pack;
  #pragma unroll
  for (int j=0;j<8;j++) pack[j] = vals[j];
  *(v8h*)(Wfrag + (size_t)gid*8) = pack;
}

// sc0 load: bypass L1, served by this XCD's L2 (where group-mates' stores/atomics land)
__device__ __forceinline__ unsigned poll_sc0(const unsigned* p){
  unsigned r;
  asm volatile("global_load_dword %0, %1, off sc0\n\ts_waitcnt vmcnt(0)"
               : "=&v"(r) : "v"(p) : "memory");
  return r;
}

// ---- persistent recurrence kernel: 256 blocks x 256 threads, 1 block/CU (96KB dyn LDS)
__global__ void __launch_bounds__(256, 1)
k_rnn(const f16* __restrict__ Wfrag, const float* __restrict__ beff,
      f16* __restrict__ hbuf, unsigned int* __restrict__ bar,
      float* __restrict__ out){
  extern __shared__ char lds_raw[];
  float*    red    = (float*)lds_raw;              // [(c*3+rank)][lane][4] f32, 15360 B
  unsigned* s_slot = (unsigned*)(lds_raw + 16384);

  const int tid  = threadIdx.x;
  const int lane = tid & 63;
  const int wv   = tid >> 6;

  // Dynamic same-XCD group formation. 1 block/CU + grid==CU count => 32 blocks/XCD.
  // Group = xcc*2 + slot/16, member = slot%16: group shares one XCD L2 BY CONSTRUCTION.
  if (tid == 0){
    unsigned xcc;
    asm volatile("s_getreg_b32 %0, hwreg(HW_REG_XCC_ID)" : "=s"(xcc));
    xcc &= 7;
    unsigned slot = atomicAdd(&bar[512 + xcc*32], 1u);  // one-time, MALL-executed, fine
    *s_slot = xcc*32 + slot;
  }
  __syncthreads();
  const unsigned sid = *s_slot;
  if ((sid & 31u) >= 32u) return;     // paranoia: never OOB if CU harvest is asymmetric
  const int g   = sid >> 4;
  const int mem = sid & 15;
  if (g >= GROUPS) return;
  const int m0   = g * 16;
  const int n0   = mem * NTILE;
  const int quad = lane >> 4;
  const int l15  = lane & 15;

  // B fragments resident in registers for the whole 511-step loop
  v8h bw[8][5];
  {
    const f16* wp = Wfrag + ((size_t)((mem*4 + wv)*40)*64 + lane)*8;
    #pragma unroll
    for (int kk=0;kk<8;kk++)
      #pragma unroll
      for (int c=0;c<5;c++)
        bw[kk][c] = *(const v8h*)(wp + (size_t)((kk*5+c)*64)*8);
  }

  const int kbase = wv*256;
  unsigned int* cnt = bar + g*32;   // one 128B line per group, lives in this XCD's L2

  for (int t=1; t<TSTEPS; ++t){
    const f16* hin  = hbuf + (size_t)((t-1)&1)*(BATCH*HIDDEN);
    f16*       hout = hbuf + (size_t)(t&1)*(BATCH*HIDDEN);

    // A fragments via sc0 loads (L1-bypass): group-mates wrote h into the shared L2.
    // lane holds A[m=lane&15][k=quad*8+j]; waves read disjoint K slices.
    v8h af[8];
    {
      const f16* abase = hin + (size_t)(m0 + l15)*HIDDEN + kbase + quad*8;
      asm volatile(
        "global_load_dwordx4 %0, %8, off sc0\n\t"
        "global_load_dwordx4 %1, %8, off offset:64 sc0\n\t"
        "global_load_dwordx4 %2, %8, off offset:128 sc0\n\t"
        "global_load_dwordx4 %3, %8, off offset:192 sc0\n\t"
        "global_load_dwordx4 %4, %8, off offset:256 sc0\n\t"
        "global_load_dwordx4 %5, %8, off offset:320 sc0\n\t"
        "global_load_dwordx4 %6, %8, off offset:384 sc0\n\t"
        "global_load_dwordx4 %7, %8, off offset:448 sc0\n\t"
        "s_waitcnt vmcnt(0)"
        : "=&v"(af[0]), "=&v"(af[1]), "=&v"(af[2]), "=&v"(af[3]),
          "=&v"(af[4]), "=&v"(af[5]), "=&v"(af[6]), "=&v"(af[7])
        : "v"(abase) : "memory");
    }

    v4f acc[5];
    #pragma unroll
    for (int c=0;c<5;c++){ v4f z = {0.f,0.f,0.f,0.f}; acc[c] = z; }

    #pragma unroll
    for (int kk=0;kk<8;kk++){
      #pragma unroll
      for (int c=0;c<5;c++)
        acc[c] = __builtin_amdgcn_mfma_f32_16x16x32_f16(af[kk], bw[kk][c], acc[c], 0,0,0);
    }

    // cross-wave K reduction via LDS. tile c owner = c&3.
    #pragma unroll
    for (int c=0;c<5;c++){
      int owner = c & 3;
      if (wv != owner){
        int rank = (wv > owner) ? wv-1 : wv;
        *(v4f*)(red + ((size_t)(c*3 + rank)*64 + lane)*4) = acc[c];
      }
    }
    __syncthreads();

    // pass 1: hidden columns (consumed by group next step) -> plain stores into L2
    #pragma unroll
    for (int c=0;c<5;c++){
      if ((c & 3) == wv){
        int colT = c*16 + l15;
        int col  = n0 + colT;
        if (col < HIDDEN && colT < NTILE){
          v4f s = acc[c];
          #pragma unroll
          for (int r=0;r<3;r++) s += *(const v4f*)(red + ((size_t)(c*3 + r)*64 + lane)*4);
          float b = beff[col];
          #pragma unroll
          for (int r=0;r<4;r++){
            float v = fast_tanh(s[r] + b);
            hout[(size_t)(m0 + quad*4 + r)*HIDDEN + col] = (f16)v;  // C/D: col=lane&15,row=quad*4+r
          }
        }
      }
    }
    __syncthreads();   // barrier implies vmcnt(0) in every wave: h stores are in L2
    if (tid == 0){
      // WORKGROUP scope => plain global_atomic_add, executes in the LOCAL XCD L2 —
      // the same L2 the sc0 polls read. No sc1, no MALL round-trip.
      __hip_atomic_fetch_add(cnt, 1u, __ATOMIC_RELAXED, __HIP_MEMORY_SCOPE_WORKGROUP);
    }
    // pass 2: y columns (consumed by nobody) — overlaps group-mates' arrival
    #pragma unroll
    for (int c=0;c<5;c++){
      if ((c & 3) == wv){
        int colT = c*16 + l15;
        int col  = n0 + colT;
        if (col >= HIDDEN && colT < NTILE){
          v4f s = acc[c];
          #pragma unroll
          for (int r=0;r<3;r++) s += *(const v4f*)(red + ((size_t)(c*3 + r)*64 + lane)*4);
          float b = beff[col];
          float* op = out + (size_t)t*(BATCH*OUTPUT) + (col - HIDDEN);
          #pragma unroll
          for (int r=0;r<4;r++)
            op[(size_t)(m0 + quad*4 + r)*OUTPUT] = s[r] + b;
        }
      }
    }
    if (tid == 0){
      // bounded spin: worst case ~0.5ms/step => fails visibly (absmax), never hangs
      unsigned tries = 0;
      while (poll_sc0(cnt) < (unsigned)(MEMB*t) && tries < 4096u){
        __builtin_amdgcn_s_sleep(2);
        ++tries;
      }
    }
    __syncthreads();
  }
}

extern "C" void kernel_launch(void* const* d_in, const int* in_sizes, int n_in,
                              void* d_out, int out_size, void* d_ws, size_t ws_size,
                              hipStream_t stream){
  const float* x0   = (const float*)d_in[0];
  const float* Wi2h = (const float*)d_in[1];
  const float* bi2h = (const float*)d_in[2];
  const float* Wh2h = (const float*)d_in[3];
  const float* bh2h = (const float*)d_in[4];
  const float* Wh2o = (const float*)d_in[5];
  const float* bh2o = (const float*)d_in[6];
  float* out = (float*)d_out;
  char* ws = (char*)d_ws;

  f16*          Wfrag = (f16*)(ws + WS_WFRAG);
  float*        beff  = (float*)(ws + WS_BEFF);
  f16*          hbuf  = (f16*)(ws + WS_HBUF);
  unsigned int* bar   = (unsigned int*)(ws + WS_BAR);

  hipMemsetAsync(bar, 0, BAR_U32S*sizeof(unsigned int), stream);
  k_bias <<<5,    256, 0, stream>>>(bi2h, bh2h, bh2o, Wi2h, beff);
  k_h1   <<<1024, 256, 0, stream>>>(x0, Wi2h, bi2h, bh2h, hbuf);
  k_copy0<<<128,  256, 0, stream>>>(x0, out);
  k_wfrag<<<640,  256, 0, stream>>>(Wh2h, Wh2o, Wi2h, Wfrag);

  // 96KB dynamic LDS forces 1 block/CU -> all 256 blocks co-resident, 32 per XCD,
  // 1 wave/SIMD -> full VGPR budget for register-resident W fragments.
  hipFuncSetAttribute((const void*)k_rnn, hipFuncAttributeMaxDynamicSharedMemorySize, 98304);
  k_rnn<<<256, 256, 98304, stream>>>(Wfrag, beff, hbuf, bar, out);
}

// Round 5
// 1724.372 us; speedup vs baseline: 142.8981x; 142.8981x over previous
//
#include <hip/hip_runtime.h>
#include <cstdint>
#include <cstddef>

// PlainRNN fused: h_{t+1} = tanh(h_t @ W_eff + b_eff), traj[t] = h_t @ W_h2o + b_h2o
// W_eff = W_h2h + W_h2o @ W_i2h  (recurrence composition removes x from the loop)
//
// Persistent kernel: 16 groups (16 batch rows each) x 16 blocks (72 of 1152 cols each).
// Groups formed DYNAMICALLY per-XCD (HW_REG_XCC_ID + per-XCD slot counter): all 16
// members share one XCD L2.
//
// R5 split of concerns (R4's sc0/workgroup pairing froze — 246ms = full spin timeout
// every step; R1 proved the agent/agent pairing works):
//   barrier: default (agent) atomicAdd arrival + agent relaxed atomic-load poll.
//            Both execute at the device coherence point. NO threadfence => no
//            buffer_wbl2/inv => h stays in L2 (R1's 406MB HBM writes came from the
//            fences, not the atomics).
//   h data:  plain stores -> XCD-local L2 (syncthreads' vmcnt(0) drains them);
//            consumers use PLAIN loads + 4-slot rotation of hbuf: reuse distance
//            4 steps x 32KB A-tile = 128KB streamed through the 32KB L1 =>
//            capacity-evicted => every A-load misses L1 and hits the shared L2.

#define BATCH  256
#define INPUT  128
#define HIDDEN 1024
#define OUTPUT 128
#define TSTEPS 512
#define NCAT   1152
#define NTILE  72
#define GROUPS 16
#define MEMB   16
#define NSLOT  4

// workspace layout (bytes)
#define WS_WFRAG 0u
#define WS_BEFF  2621440u
#define WS_HBUF  2629632u                 // 4 slots x 256x1024 f16 = 4x524288
#define WS_BAR   4726784u
// bar[] u32: [0..511] arrival counters (group g at g*32, one 128B line each)
//            [512..767] per-XCD slot counters (xcc at 512 + xcc*32)
#define BAR_U32S 768

typedef _Float16 f16;
typedef _Float16 v8h __attribute__((ext_vector_type(8)));
typedef float    v4f __attribute__((ext_vector_type(4)));

__device__ __forceinline__ float fast_tanh(float x){
  float e = __expf(2.0f * x);
  return (e - 1.0f) / (e + 1.0f);
}

// ---- bias composition
__global__ void k_bias(const float* __restrict__ bi2h, const float* __restrict__ bh2h,
                       const float* __restrict__ bh2o, const float* __restrict__ Wi2h,
                       float* __restrict__ beff){
  int n = blockIdx.x*256 + threadIdx.x;
  if (n >= 1168) return;
  float v = 0.f;
  if (n < HIDDEN){
    v = bi2h[n] + bh2h[n];
    for (int j=0;j<INPUT;j++) v += bh2o[j]*Wi2h[j*HIDDEN + n];
  } else if (n < NCAT){
    v = bh2o[n - HIDDEN];
  }
  beff[n] = v;
}

// ---- h_1 = tanh(x0 @ W_i2h + b_i2h + b_h2h) -> slot 0
__global__ void k_h1(const float* __restrict__ x0, const float* __restrict__ Wi2h,
                     const float* __restrict__ bi2h, const float* __restrict__ bh2h,
                     f16* __restrict__ hbuf){
  int idx = blockIdx.x*256 + threadIdx.x;
  int m = idx >> 10, n = idx & 1023;
  float acc = bi2h[n] + bh2h[n];
  const float* xr = x0 + m*INPUT;
  for (int j=0;j<INPUT;j++) acc += xr[j]*Wi2h[j*HIDDEN + n];
  hbuf[idx] = (f16)fast_tanh(acc);
}

// ---- traj[0] = x_0
__global__ void k_copy0(const float* __restrict__ x0, float* __restrict__ out){
  int i = blockIdx.x*256 + threadIdx.x;
  out[i] = x0[i];
}

// ---- W fragment packing: [mem 16][wave 4][kk 8][c 5][lane 64][8 halves]
__global__ void k_wfrag(const float* __restrict__ Wh2h, const float* __restrict__ Wh2o,
                        const float* __restrict__ Wi2h, f16* __restrict__ Wfrag){
  int gid = blockIdx.x*256 + threadIdx.x;
  int lane = gid & 63;
  int fi = gid >> 6;
  int c = fi % 5, kk = (fi/5) & 7, wv = (fi/40) & 3, mem = fi/160;
  int k0 = wv*256 + kk*32 + (lane>>4)*8;
  int n  = mem*NTILE + c*16 + (lane & 15);
  f16 vals[8];
  if (n >= NCAT){
    #pragma unroll
    for (int j=0;j<8;j++) vals[j] = (f16)0.f;
  } else if (n >= HIDDEN){
    #pragma unroll
    for (int j=0;j<8;j++) vals[j] = (f16)Wh2o[(k0+j)*OUTPUT + (n-HIDDEN)];
  } else {
    float acc[8];
    #pragma unroll
    for (int j=0;j<8;j++) acc[j] = Wh2h[(k0+j)*HIDDEN + n];
    for (int q=0;q<INPUT;q++){
      float wi = Wi2h[q*HIDDEN + n];
      #pragma unroll
      for (int j=0;j<8;j++) acc[j] += Wh2o[(k0+j)*OUTPUT + q]*wi;
    }
    #pragma unroll
    for (int j=0;j<8;j++) vals[j] = (f16)acc[j];
  }
  v8h pack;
  #pragma unroll
  for (int j=0;j<8;j++) pack[j] = vals[j];
  *(v8h*)(Wfrag + (size_t)gid*8) = pack;
}

// ---- persistent recurrence kernel: 256 blocks x 256 threads, 1 block/CU (96KB dyn LDS)
__global__ void __launch_bounds__(256, 1)
k_rnn(const f16* __restrict__ Wfrag, const float* __restrict__ beff,
      f16* __restrict__ hbuf, unsigned int* __restrict__ bar,
      float* __restrict__ out){
  extern __shared__ char lds_raw[];
  float*    red    = (float*)lds_raw;              // [(c*3+rank)][lane][4] f32, 15360 B
  unsigned* s_slot = (unsigned*)(lds_raw + 16384);

  const int tid  = threadIdx.x;
  const int lane = tid & 63;
  const int wv   = tid >> 6;

  // Dynamic same-XCD group formation. 1 block/CU + grid==CU count => 32 blocks/XCD.
  // Group = xcc*2 + slot/16, member = slot%16: group shares one XCD L2 BY CONSTRUCTION.
  if (tid == 0){
    unsigned xcc;
    asm volatile("s_getreg_b32 %0, hwreg(HW_REG_XCC_ID)" : "=s"(xcc));
    xcc &= 7;
    unsigned slot = atomicAdd(&bar[512 + xcc*32], 1u);  // one-time, device-scope
    *s_slot = xcc*32 + (slot & 31u);
  }
  __syncthreads();
  const unsigned sid = *s_slot;
  const int g   = sid >> 4;
  const int mem = sid & 15;
  if (g >= GROUPS) return;
  const int m0   = g * 16;
  const int n0   = mem * NTILE;
  const int quad = lane >> 4;
  const int l15  = lane & 15;

  // B fragments resident in registers for the whole 511-step loop
  v8h bw[8][5];
  {
    const f16* wp = Wfrag + ((size_t)((mem*4 + wv)*40)*64 + lane)*8;
    #pragma unroll
    for (int kk=0;kk<8;kk++)
      #pragma unroll
      for (int c=0;c<5;c++)
        bw[kk][c] = *(const v8h*)(wp + (size_t)((kk*5+c)*64)*8);
  }

  const int kbase = wv*256;
  unsigned int* cnt = bar + g*32;   // one 128B line per group

  for (int t=1; t<TSTEPS; ++t){
    const f16* hin  = hbuf + (size_t)((t-1)&(NSLOT-1))*(BATCH*HIDDEN);
    f16*       hout = hbuf + (size_t)(t&(NSLOT-1))*(BATCH*HIDDEN);

    // A fragments: plain vector loads. 4-slot rotation guarantees the L1 line for
    // this address was evicted (128KB/步 streamed) => miss L1, hit shared L2 (fresh).
    // lane holds A[m=lane&15][k=quad*8+j]; waves read disjoint K slices.
    v8h af[8];
    {
      const v8h* abase = (const v8h*)(hin + (size_t)(m0 + l15)*HIDDEN + kbase + quad*8);
      #pragma unroll
      for (int kk=0;kk<8;kk++)
        af[kk] = abase[kk*4];            // stride 32 halves = 4 v8h
    }

    v4f acc[5];
    #pragma unroll
    for (int c=0;c<5;c++){ v4f z = {0.f,0.f,0.f,0.f}; acc[c] = z; }

    #pragma unroll
    for (int kk=0;kk<8;kk++){
      #pragma unroll
      for (int c=0;c<5;c++)
        acc[c] = __builtin_amdgcn_mfma_f32_16x16x32_f16(af[kk], bw[kk][c], acc[c], 0,0,0);
    }

    // cross-wave K reduction via LDS. tile c owner = c&3.
    #pragma unroll
    for (int c=0;c<5;c++){
      int owner = c & 3;
      if (wv != owner){
        int rank = (wv > owner) ? wv-1 : wv;
        *(v4f*)(red + ((size_t)(c*3 + rank)*64 + lane)*4) = acc[c];
      }
    }
    __syncthreads();

    // pass 1: hidden columns (consumed by group next step) -> plain stores into L2
    #pragma unroll
    for (int c=0;c<5;c++){
      if ((c & 3) == wv){
        int colT = c*16 + l15;
        int col  = n0 + colT;
        if (col < HIDDEN && colT < NTILE){
          v4f s = acc[c];
          #pragma unroll
          for (int r=0;r<3;r++) s += *(const v4f*)(red + ((size_t)(c*3 + r)*64 + lane)*4);
          float b = beff[col];
          #pragma unroll
          for (int r=0;r<4;r++){
            float v = fast_tanh(s[r] + b);
            hout[(size_t)(m0 + quad*4 + r)*HIDDEN + col] = (f16)v;  // C/D: col=lane&15,row=quad*4+r
          }
        }
      }
    }
    __syncthreads();   // each wave waits vmcnt(0) before the barrier: h stores are in L2
    if (tid == 0){
      atomicAdd(cnt, 1u);   // device-scope RMW at the coherence point (R1-proven)
    }
    // pass 2: y columns (consumed by nobody) — overlaps group-mates' arrival
    #pragma unroll
    for (int c=0;c<5;c++){
      if ((c & 3) == wv){
        int colT = c*16 + l15;
        int col  = n0 + colT;
        if (col >= HIDDEN && colT < NTILE){
          v4f s = acc[c];
          #pragma unroll
          for (int r=0;r<3;r++) s += *(const v4f*)(red + ((size_t)(c*3 + r)*64 + lane)*4);
          float b = beff[col];
          float* op = out + (size_t)t*(BATCH*OUTPUT) + (col - HIDDEN);
          #pragma unroll
          for (int r=0;r<4;r++)
            op[(size_t)(m0 + quad*4 + r)*OUTPUT] = s[r] + b;
        }
      }
    }
    if (tid == 0){
      // agent relaxed atomic-load poll: same coherence point as the RMW (R1-proven).
      // Bounded: if broken, ~0.4ms/step => visible absmax failure, never a hang.
      unsigned tries = 0;
      while (__hip_atomic_load(cnt, __ATOMIC_RELAXED, __HIP_MEMORY_SCOPE_AGENT)
             < (unsigned)(MEMB*t) && tries < 2048u){
        __builtin_amdgcn_s_sleep(1);
        ++tries;
      }
    }
    __syncthreads();
  }
}

extern "C" void kernel_launch(void* const* d_in, const int* in_sizes, int n_in,
                              void* d_out, int out_size, void* d_ws, size_t ws_size,
                              hipStream_t stream){
  const float* x0   = (const float*)d_in[0];
  const float* Wi2h = (const float*)d_in[1];
  const float* bi2h = (const float*)d_in[2];
  const float* Wh2h = (const float*)d_in[3];
  const float* bh2h = (const float*)d_in[4];
  const float* Wh2o = (const float*)d_in[5];
  const float* bh2o = (const float*)d_in[6];
  float* out = (float*)d_out;
  char* ws = (char*)d_ws;

  f16*          Wfrag = (f16*)(ws + WS_WFRAG);
  float*        beff  = (float*)(ws + WS_BEFF);
  f16*          hbuf  = (f16*)(ws + WS_HBUF);
  unsigned int* bar   = (unsigned int*)(ws + WS_BAR);

  hipMemsetAsync(bar, 0, BAR_U32S*sizeof(unsigned int), stream);
  k_bias <<<5,    256, 0, stream>>>(bi2h, bh2h, bh2o, Wi2h, beff);
  k_h1   <<<1024, 256, 0, stream>>>(x0, Wi2h, bi2h, bh2h, hbuf);
  k_copy0<<<128,  256, 0, stream>>>(x0, out);
  k_wfrag<<<640,  256, 0, stream>>>(Wh2h, Wh2o, Wi2h, Wfrag);

  // 96KB dynamic LDS forces 1 block/CU -> all 256 blocks co-resident, 32 per XCD,
  // 1 wave/SIMD -> full VGPR budget for register-resident W fragments.
  hipFuncSetAttribute((const void*)k_rnn, hipFuncAttributeMaxDynamicSharedMemorySize, 98304);
  k_rnn<<<256, 256, 98304, stream>>>(Wfrag, beff, hbuf, bar, out);
}